// Round 8
// baseline (196.492 us; speedup 1.0000x reference)
//
#include <hip/hip_runtime.h>
#include <math.h>

// CapsuleLinear dynamic routing — ENTIRE op in ONE kernel, one block per batch.
//   s[b,o,i]   = sum_n prob[b,o,n] * x[b,n,i]
//   out[b,o,l] = sum_i W[o,l,i] * s[b,o,i]
//   logits[b,o,n] = x[b,n,:] . T[b,o,:],  T accumulates t_r[o,i] = sum_l W[o,l,i]*v_r[o,l]
//
// R8: R7 post-mortem — every cross-kernel consumer re-fetches inputs from
// beyond-L2 (kB FETCH 7.9 MB = x + part re-read; 51 us) and the 4-deep chain
// pays ~3 launch gaps. With one block per batch there are ZERO cross-block
// dependencies: init-reduce, T0, pass1, vt1, pass2, vt2 are all block-local,
// ordered by __syncthreads() only — no fences (R1), no grid.sync (R5), no
// boundaries (R4/R7). x is read from HBM once; part/T never exist in global.
// 32 blocks x 512 threads (8 waves, 1 block/CU, 4 blocks/XCD -> x slab + W
// L2-resident after phase 0). Pass body = R4-proven (broadcast VMEM rows,
// DPP+shfl softmax, pinned t[]) but processes 4 n per group with interleaved
// softmax chains (ILP on the serial reduction chain). Declared risk: ~215
// live VGPRs; if >256 the compiler spills (correct, slower) — bisect would
// be 2-row groups.

#define N_B      32
#define IN_CAPS  1152
#define IN_LEN   32
#define OUT_CAPS 64
#define OUT_LEN  32

#define WAVES    8
#define THREADS  512
#define NPW      (IN_CAPS / WAVES)    // 144 n per wave
#define NGRP     (NPW / 4)            // 36 groups of 4 n
#define TSTR     36                   // padded LDS row stride (floats)

// DPP helper: butterfly step, all lanes valid.
#define DPPV(v, ctrl) \
    __int_as_float(__builtin_amdgcn_update_dpp(0, __float_as_int(v), ctrl, 0xF, 0xF, true))

__device__ __forceinline__ float wave_max(float v) {
    v = fmaxf(v, DPPV(v, 0xB1));         // quad_perm xor1
    v = fmaxf(v, DPPV(v, 0x4E));         // quad_perm xor2
    v = fmaxf(v, DPPV(v, 0x141));        // row_half_mirror (xor4 within 8)
    v = fmaxf(v, DPPV(v, 0x140));        // row_mirror (xor8 within 16)
    v = fmaxf(v, __shfl_xor(v, 16, 64)); // cross-row (proven path)
    v = fmaxf(v, __shfl_xor(v, 32, 64));
    return v;
}
__device__ __forceinline__ float wave_sum(float v) {
    v += DPPV(v, 0xB1);
    v += DPPV(v, 0x4E);
    v += DPPV(v, 0x141);
    v += DPPV(v, 0x140);
    v += __shfl_xor(v, 16, 64);
    v += __shfl_xor(v, 32, 64);
    return v;
}

// ---------------------------------------------------------------------------
// k_all: one block = one batch. 8 waves x 512 threads.
// LDS: T_lds 9 KB + stage 72 KB + s_red 9 KB = 90 KB -> 1 block/CU.
// ---------------------------------------------------------------------------
__global__ __launch_bounds__(THREADS, 2) void k_all(const float* __restrict__ x,
                                                    const float* __restrict__ W,
                                                    float* __restrict__ out) {
    const int b    = blockIdx.x;
    const int tid  = threadIdx.x;
    const int lane = tid & 63;            // = output capsule o in the pass
    const int wave = __builtin_amdgcn_readfirstlane(tid >> 6);

    __shared__ __align__(16) float T_lds[OUT_CAPS * TSTR];           //  9,216 B
    __shared__ __align__(16) float stage[WAVES * OUT_CAPS * TSTR];   // 73,728 B
    __shared__ __align__(16) float s_red[OUT_CAPS * TSTR];           //  9,216 B

    const float* xb = x + (size_t)b * IN_CAPS * IN_LEN;

    // aliased scratch inside stage (disjoint float ranges):
    //   red4: floats [0, 2048)   (64 groups x 8 float4)
    //   u   : floats [2048, 4096)
    //   scale: floats [4096, 4160)
    //   s0  : floats [4224, 4256)
    float4* red4  = (float4*)stage;
    float*  u     = stage + 2048;
    float*  scale = stage + 4096;
    float*  s0    = stage + 4224;

    // ======== phase 0: s0 = (1/64) sum_n x[b,n,:]  (single cold HBM read) ===
    {
        const int q = tid & 7, g = tid >> 3;      // g 0..63
        float4 acc = make_float4(0.f, 0.f, 0.f, 0.f);
        for (int n = g; n < IN_CAPS; n += 64) {   // 18 independent loads
            const float4 v = *(const float4*)(xb + n * IN_LEN + q * 4);
            acc.x += v.x; acc.y += v.y; acc.z += v.z; acc.w += v.w;
        }
        red4[g * 8 + q] = acc;
    }
    __syncthreads();
    if (tid < 8) {
        float4 v = make_float4(0.f, 0.f, 0.f, 0.f);
#pragma unroll 16
        for (int g = 0; g < 64; ++g) {
            const float4 r = red4[g * 8 + tid];
            v.x += r.x; v.y += r.y; v.z += r.z; v.w += r.w;
        }
        const float inv = 1.f / 64.f;             // uniform softmax prob at r=0
        s0[tid * 4 + 0] = v.x * inv;
        s0[tid * 4 + 1] = v.y * inv;
        s0[tid * 4 + 2] = v.z * inv;
        s0[tid * 4 + 3] = v.w * inv;
    }
    __syncthreads();

    // ======== phase 1: u = W@s0; squash; T0 -> T_lds ========================
    for (int e = tid; e < OUT_CAPS * OUT_LEN; e += THREADS) {
        const float* wrow = W + (size_t)e * IN_LEN;
        float a = 0.f;
#pragma unroll
        for (int i = 0; i < IN_LEN; ++i) a = fmaf(wrow[i], s0[i], a);
        u[e] = a;
    }
    __syncthreads();
    if (tid < OUT_CAPS) {
        float ns = 0.f;
#pragma unroll
        for (int l = 0; l < OUT_LEN; ++l) { const float v = u[tid * OUT_LEN + l]; ns = fmaf(v, v, ns); }
        scale[tid] = sqrtf(ns) / (1.f + ns);
    }
    __syncthreads();
    for (int e = tid; e < OUT_CAPS * IN_LEN; e += THREADS) {
        const int o = e >> 5, i = e & 31;
        float a = 0.f;
#pragma unroll
        for (int l = 0; l < OUT_LEN; ++l)
            a = fmaf(W[((size_t)o * OUT_LEN + l) * IN_LEN + i], u[o * OUT_LEN + l], a);
        T_lds[o * TSTR + i] = a * scale[o];
    }
    __syncthreads();

    // ======== pass phase (R4 body, 4-way n-interleaved), used twice =========
    auto do_pass = [&]() {
        float t[IN_LEN];
#pragma unroll
        for (int q = 0; q < 8; ++q) {
            const float4 v = *(const float4*)&T_lds[lane * TSTR + q * 4];
            t[4 * q] = v.x; t[4 * q + 1] = v.y; t[4 * q + 2] = v.z; t[4 * q + 3] = v.w;
        }
        asm volatile("" : "+v"(t[0]), "+v"(t[1]), "+v"(t[2]), "+v"(t[3]),
                          "+v"(t[4]), "+v"(t[5]), "+v"(t[6]), "+v"(t[7]),
                          "+v"(t[8]), "+v"(t[9]), "+v"(t[10]), "+v"(t[11]),
                          "+v"(t[12]), "+v"(t[13]), "+v"(t[14]), "+v"(t[15]));
        asm volatile("" : "+v"(t[16]), "+v"(t[17]), "+v"(t[18]), "+v"(t[19]),
                          "+v"(t[20]), "+v"(t[21]), "+v"(t[22]), "+v"(t[23]),
                          "+v"(t[24]), "+v"(t[25]), "+v"(t[26]), "+v"(t[27]),
                          "+v"(t[28]), "+v"(t[29]), "+v"(t[30]), "+v"(t[31]));

        float s[IN_LEN];
#pragma unroll
        for (int i = 0; i < IN_LEN; ++i) s[i] = 0.f;

        const float* xw = xb + (size_t)wave * NPW * IN_LEN;

        for (int g = 0; g < NGRP; ++g) {               // 36 groups of 4 rows
            const float4* xr = (const float4*)(xw + (size_t)g * 4 * IN_LEN);
            float4 r[4][8];                             // 128 VGPR, const-indexed
#pragma unroll
            for (int k = 0; k < 4; ++k)
#pragma unroll
                for (int q = 0; q < 8; ++q)
                    r[k][q] = xr[k * 8 + q];            // wave-uniform broadcast

            float lg[4];
#pragma unroll
            for (int k = 0; k < 4; ++k) {
                float a = 0.f;
#pragma unroll
                for (int q = 0; q < 8; ++q) {
                    a = fmaf(r[k][q].x, t[4 * q + 0], a);
                    a = fmaf(r[k][q].y, t[4 * q + 1], a);
                    a = fmaf(r[k][q].z, t[4 * q + 2], a);
                    a = fmaf(r[k][q].w, t[4 * q + 3], a);
                }
                lg[k] = a;
            }

            // 4 independent softmax chains -> scheduler interleaves them
            float m[4], p[4], S[4], prob[4];
#pragma unroll
            for (int k = 0; k < 4; ++k) m[k] = wave_max(lg[k]);
#pragma unroll
            for (int k = 0; k < 4; ++k) p[k] = __expf(lg[k] - m[k]);
#pragma unroll
            for (int k = 0; k < 4; ++k) S[k] = wave_sum(p[k]);
#pragma unroll
            for (int k = 0; k < 4; ++k) prob[k] = p[k] * __builtin_amdgcn_rcpf(S[k]);

#pragma unroll
            for (int q = 0; q < 8; ++q)
#pragma unroll
                for (int k = 0; k < 4; ++k) {
                    s[4 * q + 0] = fmaf(prob[k], r[k][q].x, s[4 * q + 0]);
                    s[4 * q + 1] = fmaf(prob[k], r[k][q].y, s[4 * q + 1]);
                    s[4 * q + 2] = fmaf(prob[k], r[k][q].z, s[4 * q + 2]);
                    s[4 * q + 3] = fmaf(prob[k], r[k][q].w, s[4 * q + 3]);
                }
        }

        // flush wave partial into stage
        {
            float4* dst = (float4*)&stage[(wave * OUT_CAPS + lane) * TSTR];
#pragma unroll
            for (int q = 0; q < 8; ++q)
                dst[q] = make_float4(s[4 * q], s[4 * q + 1], s[4 * q + 2], s[4 * q + 3]);
        }
        __syncthreads();
    };

    // ======== vt phase: reduce 8 wave partials -> u -> squash ===============
    auto do_vt = [&](int final_iter) {
        // one float4 per thread: 512 = 64 o x 8 q
        {
            const int o = tid >> 3, q4 = (tid & 7) * 4;
            float4 a = make_float4(0.f, 0.f, 0.f, 0.f);
#pragma unroll
            for (int w = 0; w < WAVES; ++w) {
                const float4 v = *(const float4*)&stage[(w * OUT_CAPS + o) * TSTR + q4];
                a.x += v.x; a.y += v.y; a.z += v.z; a.w += v.w;
            }
            *(float4*)&s_red[o * TSTR + q4] = a;
        }
        __syncthreads();                  // reduce reads of stage done; s_red ready

        for (int e = tid; e < OUT_CAPS * OUT_LEN; e += THREADS) {
            const int o = e >> 5;
            const float* wrow = W + (size_t)e * IN_LEN;
            const float* srow = s_red + o * TSTR;
            float a = 0.f;
#pragma unroll
            for (int i = 0; i < IN_LEN; ++i) a = fmaf(wrow[i], srow[i], a);
            u[e] = a;                     // overwrites stage[2048..4096) — post-barrier
        }
        __syncthreads();
        if (tid < OUT_CAPS) {
            float ns = 0.f;
#pragma unroll
            for (int l = 0; l < OUT_LEN; ++l) { const float v = u[tid * OUT_LEN + l]; ns = fmaf(v, v, ns); }
            scale[tid] = sqrtf(ns) / (1.f + ns);
        }
        __syncthreads();

        if (final_iter) {
            for (int e = tid; e < OUT_CAPS * OUT_LEN; e += THREADS)
                out[(size_t)b * OUT_CAPS * OUT_LEN + e] = u[e] * scale[e >> 5];
        } else {
            for (int e = tid; e < OUT_CAPS * IN_LEN; e += THREADS) {
                const int o = e >> 5, i = e & 31;
                float a = 0.f;
#pragma unroll
                for (int l = 0; l < OUT_LEN; ++l)
                    a = fmaf(W[((size_t)o * OUT_LEN + l) * IN_LEN + i], u[o * OUT_LEN + l], a);
                T_lds[o * TSTR + i] += a * scale[o];
            }
            __syncthreads();
        }
    };

    // ======== routing: pass1 -> vt1 -> pass2 -> vt2(final) ==================
    do_pass();
    do_vt(0);
    do_pass();
    do_vt(1);
}

extern "C" void kernel_launch(void* const* d_in, const int* in_sizes, int n_in,
                              void* d_out, int out_size, void* d_ws, size_t ws_size,
                              hipStream_t stream) {
    const float* x = (const float*)d_in[0];   // [32,1152,32]
    const float* W = (const float*)d_in[1];   // [64,32,32]
    float* out = (float*)d_out;               // [32,64,32]
    (void)d_ws; (void)ws_size;                // no global scratch needed

    k_all<<<N_B, THREADS, 0, stream>>>(x, W, out);
}